// Round 3
// baseline (765.135 us; speedup 1.0000x reference)
//
#include <hip/hip_runtime.h>

#define IN_C 128
#define NEG 0.2f
#define GAT_EPS 1e-16f

// ---------------- Layer 1: x[N,128] @ W1[128,64] -> h1[N,64]; a_src1/a_dst1[N,8]
__global__ __launch_bounds__(256) void gemm1_kernel(
    const float* __restrict__ x, const float* __restrict__ W1,
    const float* __restrict__ att_s1, const float* __restrict__ att_d1,
    float* __restrict__ h1, float* __restrict__ a_src1, float* __restrict__ a_dst1,
    int N)
{
    __shared__ float w1s[IN_C * 64];
    __shared__ float xs[4][IN_C];
    int tid = threadIdx.x;
    for (int i = tid; i < IN_C * 64; i += 256) w1s[i] = W1[i];
    int lane = tid & 63, wid = tid >> 6;
    float att_s = att_s1[lane];   // att_src1 is [8][8] row-major: idx = head*8+c = lane
    float att_d = att_d1[lane];
    int ngroups = (N + 3) >> 2;
    for (int grp = blockIdx.x; grp < ngroups; grp += gridDim.x) {
        int nbase = grp * 4;
        __syncthreads();
        for (int i = tid; i < 4 * IN_C; i += 256) {
            int nn = nbase + (i >> 7);
            xs[i >> 7][i & 127] = (nn < N) ? x[(size_t)nn * IN_C + (i & 127)] : 0.f;
        }
        __syncthreads();
        int n = nbase + wid;
        const float* xr = xs[wid];
        float acc = 0.f;
        #pragma unroll 8
        for (int c = 0; c < IN_C; ++c)
            acc = fmaf(xr[c], w1s[c * 64 + lane], acc);
        if (n < N) {
            h1[(size_t)n * 64 + lane] = acc;
            float rs = acc * att_s;
            float rd = acc * att_d;
            rs += __shfl_xor(rs, 1); rd += __shfl_xor(rd, 1);
            rs += __shfl_xor(rs, 2); rd += __shfl_xor(rd, 2);
            rs += __shfl_xor(rs, 4); rd += __shfl_xor(rd, 4);
            if ((lane & 7) == 0) {
                a_src1[n * 8 + (lane >> 3)] = rs;
                a_dst1[n * 8 + (lane >> 3)] = rd;
            }
        }
    }
}

// ---------------- Layer 1 edge pass: unnormalized softmax-weighted aggregation
__global__ __launch_bounds__(256) void edge1_kernel(
    const int* __restrict__ ei, const float* __restrict__ a_src1,
    const float* __restrict__ a_dst1, const float* __restrict__ h1,
    float* __restrict__ out1, float* __restrict__ asum1,
    int E, int Etot)
{
    long long gid = (long long)blockIdx.x * 256 + threadIdx.x;
    int e = (int)(gid >> 6);
    if (e >= Etot) return;
    int j = (int)(gid & 63);
    int src, dst;
    if (e < E) { src = ei[e]; dst = ei[E + e]; }
    else       { src = dst = e - E; }              // self-loops appended
    int h = j >> 3;
    float a = a_src1[src * 8 + h] + a_dst1[dst * 8 + h];
    float la = (a > 0.f) ? a : NEG * a;
    float w = __expf(la);                           // max-subtraction skipped (safe: |a| small)
    float hv = h1[(size_t)src * 64 + j];
    atomicAdd(&out1[(size_t)dst * 64 + j], w * hv);
    if ((j & 7) == 0) atomicAdd(&asum1[dst * 8 + h], w);
}

// ---------------- Layer 1 finalize: h2 = relu(out1/(asum1+eps) + b1)
__global__ __launch_bounds__(256) void fin1_kernel(
    const float* __restrict__ out1, const float* __restrict__ asum1,
    const float* __restrict__ b1, float* __restrict__ h2, int N)
{
    int i = blockIdx.x * 256 + threadIdx.x;
    if (i >= N * 64) return;
    int n = i >> 6, j = i & 63;
    float v = out1[i] / (asum1[n * 8 + (j >> 3)] + GAT_EPS) + b1[j];
    h2[i] = v > 0.f ? v : 0.f;
}

// ---------------- Layer 2: h2[N,64] @ W2[64,16] -> h2w[N,16]; a_src2/a_dst2[N]
__global__ __launch_bounds__(256) void gemm2_kernel(
    const float* __restrict__ h2, const float* __restrict__ W2,
    const float* __restrict__ att_s2, const float* __restrict__ att_d2,
    float* __restrict__ h2w, float* __restrict__ a_src2, float* __restrict__ a_dst2,
    int N)
{
    __shared__ float w2s[64 * 16];
    __shared__ float hs[16][64];
    int tid = threadIdx.x;
    for (int i = tid; i < 64 * 16; i += 256) w2s[i] = W2[i];
    int lane = tid & 63, wid = tid >> 6;
    int j = lane & 15, jn = lane >> 4;
    float att_s = att_s2[j], att_d = att_d2[j];
    int ngroups = (N + 15) >> 4;
    for (int grp = blockIdx.x; grp < ngroups; grp += gridDim.x) {
        int nbase = grp * 16;
        __syncthreads();
        for (int i = tid; i < 16 * 64; i += 256) {
            int nn = nbase + (i >> 6);
            hs[i >> 6][i & 63] = (nn < N) ? h2[(size_t)nn * 64 + (i & 63)] : 0.f;
        }
        __syncthreads();
        int local = wid * 4 + jn;
        int n = nbase + local;
        float acc = 0.f;
        #pragma unroll 8
        for (int c = 0; c < 64; ++c)
            acc = fmaf(hs[local][c], w2s[c * 16 + j], acc);
        if (n < N) {
            h2w[n * 16 + j] = acc;
            float rs = acc * att_s, rd = acc * att_d;
            rs += __shfl_xor(rs, 1); rd += __shfl_xor(rd, 1);
            rs += __shfl_xor(rs, 2); rd += __shfl_xor(rd, 2);
            rs += __shfl_xor(rs, 4); rd += __shfl_xor(rd, 4);
            rs += __shfl_xor(rs, 8); rd += __shfl_xor(rd, 8);
            if (j == 0) { a_src2[n] = rs; a_dst2[n] = rd; }
        }
    }
}

// ---------------- Layer 2 edge pass
__global__ __launch_bounds__(256) void edge2_kernel(
    const int* __restrict__ ei, const float* __restrict__ a_src2,
    const float* __restrict__ a_dst2, const float* __restrict__ h2w,
    float* __restrict__ out2, float* __restrict__ asum2,
    int E, int Etot)
{
    long long gid = (long long)blockIdx.x * 256 + threadIdx.x;
    int e = (int)(gid >> 4);
    if (e >= Etot) return;
    int j = (int)(gid & 15);
    int src, dst;
    if (e < E) { src = ei[e]; dst = ei[E + e]; }
    else       { src = dst = e - E; }
    float a = a_src2[src] + a_dst2[dst];
    float la = (a > 0.f) ? a : NEG * a;
    float w = __expf(la);
    atomicAdd(&out2[dst * 16 + j], w * h2w[src * 16 + j]);
    if (j == 0) atomicAdd(&asum2[dst], w);
}

// ---------------- Layer 2 finalize -> d_out
__global__ __launch_bounds__(256) void fin2_kernel(
    const float* __restrict__ out2, const float* __restrict__ asum2,
    const float* __restrict__ b2, float* __restrict__ out, int N)
{
    int i = blockIdx.x * 256 + threadIdx.x;
    if (i >= N * 16) return;
    int n = i >> 4, j = i & 15;
    float v = out2[i] / (asum2[n] + GAT_EPS) + b2[j];
    out[i] = v > 0.f ? v : 0.f;
}

extern "C" void kernel_launch(void* const* d_in, const int* in_sizes, int n_in,
                              void* d_out, int out_size, void* d_ws, size_t ws_size,
                              hipStream_t stream)
{
    const float* x      = (const float*)d_in[0];
    const int*   ei     = (const int*)  d_in[1];   // [2,E] int32
    const float* W1     = (const float*)d_in[2];
    const float* att_s1 = (const float*)d_in[3];
    const float* att_d1 = (const float*)d_in[4];
    const float* b1     = (const float*)d_in[5];
    const float* W2     = (const float*)d_in[6];
    const float* att_s2 = (const float*)d_in[7];
    const float* att_d2 = (const float*)d_in[8];
    const float* b2     = (const float*)d_in[9];
    float* out = (float*)d_out;

    int N = in_sizes[0] / IN_C;
    int E = in_sizes[1] / 2;
    int Etot = E + N;

    float* ws = (float*)d_ws;
    float* h1     = ws;                        // N*64  (reused as h2 after fin1)
    float* out1   = h1     + (size_t)N * 64;   // N*64  \ contiguous: zeroed together
    float* asum1  = out1   + (size_t)N * 64;   // N*8   /
    float* a_src1 = asum1  + (size_t)N * 8;    // N*8
    float* a_dst1 = a_src1 + (size_t)N * 8;    // N*8
    float* h2w    = a_dst1 + (size_t)N * 8;    // N*16
    float* out2   = h2w    + (size_t)N * 16;   // N*16  \ contiguous: zeroed together
    float* asum2  = out2   + (size_t)N * 16;   // N     /
    float* a_src2 = asum2  + (size_t)N;        // N
    float* a_dst2 = a_src2 + (size_t)N;        // N

    hipMemsetAsync(out1, 0, (size_t)N * 72 * sizeof(float), stream);  // out1 + asum1
    hipMemsetAsync(out2, 0, (size_t)N * 17 * sizeof(float), stream);  // out2 + asum2

    gemm1_kernel<<<1024, 256, 0, stream>>>(x, W1, att_s1, att_d1, h1, a_src1, a_dst1, N);

    {
        long long tot = (long long)Etot * 64;
        int g = (int)((tot + 255) / 256);
        edge1_kernel<<<g, 256, 0, stream>>>(ei, a_src1, a_dst1, h1, out1, asum1, E, Etot);
    }
    {
        int g = (N * 64 + 255) / 256;
        fin1_kernel<<<g, 256, 0, stream>>>(out1, asum1, b1, h1, N);  // h2 overwrites h1
    }

    gemm2_kernel<<<1024, 256, 0, stream>>>(h1, W2, att_s2, att_d2, h2w, a_src2, a_dst2, N);

    {
        long long tot = (long long)Etot * 16;
        int g = (int)((tot + 255) / 256);
        edge2_kernel<<<g, 256, 0, stream>>>(ei, a_src2, a_dst2, h2w, out2, asum2, E, Etot);
    }
    {
        int g = (N * 16 + 255) / 256;
        fin2_kernel<<<g, 256, 0, stream>>>(out2, asum2, b2, out, N);
    }
}

// Round 5
// 504.831 us; speedup vs baseline: 1.5156x; 1.5156x over previous
//
#include <hip/hip_runtime.h>

#define IN_C 128
#define NEG 0.2f
#define GAT_EPS 1e-16f
#define CHUNK 1024   // scan chunk: supports N <= 128*1024 (N=100000 -> nb=98 <= 128)

// ---------------- Layer 1 GEMM: x[N,128] @ W1[128,64] -> h1[N,64]; a_src1/a_dst1[N,8]
__global__ __launch_bounds__(256) void gemm1_kernel(
    const float* __restrict__ x, const float* __restrict__ W1,
    const float* __restrict__ att_s1, const float* __restrict__ att_d1,
    float* __restrict__ h1, float* __restrict__ a_src1, float* __restrict__ a_dst1,
    int N)
{
    __shared__ float w1s[IN_C * 64];
    __shared__ float xs[4][IN_C];
    int tid = threadIdx.x;
    for (int i = tid; i < IN_C * 64; i += 256) w1s[i] = W1[i];
    int lane = tid & 63, wid = tid >> 6;
    float att_s = att_s1[lane];   // att_src1 [8][8] row-major; lane = head*8+c
    float att_d = att_d1[lane];
    int ngroups = (N + 3) >> 2;
    for (int grp = blockIdx.x; grp < ngroups; grp += gridDim.x) {
        int nbase = grp * 4;
        __syncthreads();
        for (int i = tid; i < 4 * IN_C; i += 256) {
            int nn = nbase + (i >> 7);
            xs[i >> 7][i & 127] = (nn < N) ? x[(size_t)nn * IN_C + (i & 127)] : 0.f;
        }
        __syncthreads();
        int n = nbase + wid;
        const float* xr = xs[wid];
        float acc = 0.f;
        #pragma unroll 8
        for (int c = 0; c < IN_C; ++c)
            acc = fmaf(xr[c], w1s[c * 64 + lane], acc);
        if (n < N) {
            h1[(size_t)n * 64 + lane] = acc;
            float rs = acc * att_s;
            float rd = acc * att_d;
            rs += __shfl_xor(rs, 1); rd += __shfl_xor(rd, 1);
            rs += __shfl_xor(rs, 2); rd += __shfl_xor(rd, 2);
            rs += __shfl_xor(rs, 4); rd += __shfl_xor(rd, 4);
            if ((lane & 7) == 0) {
                a_src1[n * 8 + (lane >> 3)] = rs;
                a_dst1[n * 8 + (lane >> 3)] = rd;
            }
        }
    }
}

// ---------------- CSR build: histogram of dst degree
__global__ __launch_bounds__(256) void hist_kernel(
    const int* __restrict__ ei, int* __restrict__ deg, int E, int Etot)
{
    int e = blockIdx.x * 256 + threadIdx.x;
    if (e >= Etot) return;
    int dst = (e < E) ? ei[E + e] : e - E;   // self-loops appended
    atomicAdd(&deg[dst], 1);
}

// per-chunk sums (CHUNK=1024 elems per block of 256 threads)
__global__ __launch_bounds__(256) void chunksum_kernel(
    const int* __restrict__ deg, int* __restrict__ csum, int N)
{
    int b = blockIdx.x, t = threadIdx.x;
    int base = b * CHUNK + t * 4;
    int s = 0;
    #pragma unroll
    for (int k = 0; k < 4; ++k) { int i = base + k; if (i < N) s += deg[i]; }
    for (int off = 32; off; off >>= 1) s += __shfl_down(s, off);
    __shared__ int ws[4];
    int lane = t & 63, wid = t >> 6;
    if (lane == 0) ws[wid] = s;
    __syncthreads();
    if (t == 0) csum[b] = ws[0] + ws[1] + ws[2] + ws[3];
}

// exclusive scan of chunk sums (single block, nb <= 128)
__global__ __launch_bounds__(128) void scan_csum_kernel(int* __restrict__ csum, int nb)
{
    int t = threadIdx.x;
    int v = (t < nb) ? csum[t] : 0;
    int lane = t & 63, wid = t >> 6;
    int s = v;
    for (int off = 1; off < 64; off <<= 1) {
        int u = __shfl_up(s, off);
        if (lane >= off) s += u;
    }
    __shared__ int ws[2];
    if (lane == 63) ws[wid] = s;
    __syncthreads();
    if (wid == 1) s += ws[0];
    if (t < nb) csum[t] = s - v;   // exclusive
}

// per-chunk exclusive scan + chunk offset -> cursor (row starts)
__global__ __launch_bounds__(256) void scan_chunk_kernel(
    const int* __restrict__ deg, const int* __restrict__ csum,
    int* __restrict__ cursor, int N)
{
    int b = blockIdx.x, t = threadIdx.x;
    int base = b * CHUNK + t * 4;
    int v[4]; int s = 0;
    #pragma unroll
    for (int k = 0; k < 4; ++k) { int i = base + k; v[k] = (i < N) ? deg[i] : 0; s += v[k]; }
    int tsum = s;
    int lane = t & 63, wid = t >> 6;
    for (int off = 1; off < 64; off <<= 1) {
        int u = __shfl_up(s, off);
        if (lane >= off) s += u;
    }
    __shared__ int ws[4];
    if (lane == 63) ws[wid] = s;
    __syncthreads();
    int woff = 0;
    for (int w = 0; w < wid; ++w) woff += ws[w];
    int excl = csum[b] + woff + (s - tsum);
    #pragma unroll
    for (int k = 0; k < 4; ++k) {
        int i = base + k;
        if (i < N) { cursor[i] = excl; excl += v[k]; }
    }
}

// scatter src by dst; after this, cursor[n] = row_end(n)  (start = end - deg[n])
__global__ __launch_bounds__(256) void scatter_kernel(
    const int* __restrict__ ei, int* __restrict__ cursor, int* __restrict__ esrc,
    int E, int Etot)
{
    int e = blockIdx.x * 256 + threadIdx.x;
    if (e >= Etot) return;
    int src, dst;
    if (e < E) { src = ei[e]; dst = ei[E + e]; }
    else       { src = dst = e - E; }
    int pos = atomicAdd(&cursor[dst], 1);
    esrc[pos] = src;
}

// ---------------- Layer 1 aggregation: one wave per dst, no float atomics.
// lane j = head(j>>3)*8 + channel; all 8 lanes of a head share the same w,
// so per-lane wsum already equals the head's softmax denominator.
__global__ __launch_bounds__(256) void agg1_kernel(
    const int* __restrict__ esrc, const int* __restrict__ cursor,
    const int* __restrict__ deg, const float* __restrict__ a_src1,
    const float* __restrict__ a_dst1, const float* __restrict__ h1,
    const float* __restrict__ b1, float* __restrict__ h2, int N)
{
    int wglobal = (blockIdx.x * 256 + threadIdx.x) >> 6;
    int nwaves = (gridDim.x * 256) >> 6;
    int lane = threadIdx.x & 63;
    int h = lane >> 3;
    float bj = b1[lane];
    for (int n = wglobal; n < N; n += nwaves) {
        int end = cursor[n], d = deg[n];
        int p = end - d;
        float ad = a_dst1[n * 8 + h];
        float acc = 0.f, wsum = 0.f;
        for (; p + 1 < end; p += 2) {            // 2-deep to break the load chain
            int s0 = esrc[p], s1 = esrc[p + 1];
            float a0 = a_src1[s0 * 8 + h] + ad;
            float a1 = a_src1[s1 * 8 + h] + ad;
            a0 = (a0 > 0.f) ? a0 : NEG * a0;
            a1 = (a1 > 0.f) ? a1 : NEG * a1;
            float w0 = __expf(a0), w1 = __expf(a1);
            float v0 = h1[(size_t)s0 * 64 + lane];
            float v1 = h1[(size_t)s1 * 64 + lane];
            acc = fmaf(w0, v0, acc);
            acc = fmaf(w1, v1, acc);
            wsum += w0 + w1;
        }
        if (p < end) {
            int s0 = esrc[p];
            float a0 = a_src1[s0 * 8 + h] + ad;
            a0 = (a0 > 0.f) ? a0 : NEG * a0;
            float w0 = __expf(a0);
            acc = fmaf(w0, h1[(size_t)s0 * 64 + lane], acc);
            wsum += w0;
        }
        float v = acc / (wsum + GAT_EPS) + bj;
        h2[(size_t)n * 64 + lane] = v > 0.f ? v : 0.f;   // fused relu(norm + bias)
    }
}

// ---------------- Layer 2 GEMM: h2[N,64] @ W2[64,16]; a_src2/a_dst2[N]
__global__ __launch_bounds__(256) void gemm2_kernel(
    const float* __restrict__ h2, const float* __restrict__ W2,
    const float* __restrict__ att_s2, const float* __restrict__ att_d2,
    float* __restrict__ h2w, float* __restrict__ a_src2, float* __restrict__ a_dst2,
    int N)
{
    __shared__ float w2s[64 * 16];
    __shared__ float hs[16][64];
    int tid = threadIdx.x;
    for (int i = tid; i < 64 * 16; i += 256) w2s[i] = W2[i];
    int lane = tid & 63, wid = tid >> 6;
    int j = lane & 15, jn = lane >> 4;
    float att_s = att_s2[j], att_d = att_d2[j];
    int ngroups = (N + 15) >> 4;
    for (int grp = blockIdx.x; grp < ngroups; grp += gridDim.x) {
        int nbase = grp * 16;
        __syncthreads();
        for (int i = tid; i < 16 * 64; i += 256) {
            int nn = nbase + (i >> 6);
            hs[i >> 6][i & 63] = (nn < N) ? h2[(size_t)nn * 64 + (i & 63)] : 0.f;
        }
        __syncthreads();
        int local = wid * 4 + jn;
        int n = nbase + local;
        float acc = 0.f;
        #pragma unroll 8
        for (int c = 0; c < 64; ++c)
            acc = fmaf(hs[local][c], w2s[c * 16 + j], acc);
        if (n < N) {
            h2w[n * 16 + j] = acc;
            float rs = acc * att_s, rd = acc * att_d;
            rs += __shfl_xor(rs, 1); rd += __shfl_xor(rd, 1);
            rs += __shfl_xor(rs, 2); rd += __shfl_xor(rd, 2);
            rs += __shfl_xor(rs, 4); rd += __shfl_xor(rd, 4);
            rs += __shfl_xor(rs, 8); rd += __shfl_xor(rd, 8);
            if (j == 0) { a_src2[n] = rs; a_dst2[n] = rd; }
        }
    }
}

// ---------------- Layer 2 aggregation: one wave per dst; 4 edges in flight
// (lane = eo*16 + j); all 16 lanes of an eo-group share w.
__global__ __launch_bounds__(256) void agg2_kernel(
    const int* __restrict__ esrc, const int* __restrict__ cursor,
    const int* __restrict__ deg, const float* __restrict__ a_src2,
    const float* __restrict__ a_dst2, const float* __restrict__ h2w,
    const float* __restrict__ b2, float* __restrict__ out, int N)
{
    int wglobal = (blockIdx.x * 256 + threadIdx.x) >> 6;
    int nwaves = (gridDim.x * 256) >> 6;
    int lane = threadIdx.x & 63;
    int j = lane & 15, eo = lane >> 4;
    float bj = b2[j];
    for (int n = wglobal; n < N; n += nwaves) {
        int end = cursor[n], d = deg[n];
        int start = end - d;
        float ad = a_dst2[n];
        float acc = 0.f, wsum = 0.f;
        for (int p = start + eo; p < end; p += 4) {
            int s = esrc[p];
            float a = a_src2[s] + ad;
            a = (a > 0.f) ? a : NEG * a;
            float w = __expf(a);
            acc = fmaf(w, h2w[(size_t)s * 16 + j], acc);
            wsum += w;
        }
        acc += __shfl_xor(acc, 16); wsum += __shfl_xor(wsum, 16);
        acc += __shfl_xor(acc, 32); wsum += __shfl_xor(wsum, 32);
        if (eo == 0) {
            float v = acc / (wsum + GAT_EPS) + bj;
            out[(size_t)n * 16 + j] = v > 0.f ? v : 0.f;
        }
    }
}

extern "C" void kernel_launch(void* const* d_in, const int* in_sizes, int n_in,
                              void* d_out, int out_size, void* d_ws, size_t ws_size,
                              hipStream_t stream)
{
    const float* x      = (const float*)d_in[0];
    const int*   ei     = (const int*)  d_in[1];   // [2,E] int32
    const float* W1     = (const float*)d_in[2];
    const float* att_s1 = (const float*)d_in[3];
    const float* att_d1 = (const float*)d_in[4];
    const float* b1     = (const float*)d_in[5];
    const float* W2     = (const float*)d_in[6];
    const float* att_s2 = (const float*)d_in[7];
    const float* att_d2 = (const float*)d_in[8];
    const float* b2     = (const float*)d_in[9];
    float* out = (float*)d_out;

    int N = in_sizes[0] / IN_C;
    int E = in_sizes[1] / 2;
    int Etot = E + N;
    int nb = (N + CHUNK - 1) / CHUNK;   // 98 for N=100000 (must be <= 128)

    // workspace layout (floats then ints)
    float* ws = (float*)d_ws;
    float* h1     = ws;                        // N*64
    float* h2     = h1     + (size_t)N * 64;   // N*64
    float* a_src1 = h2     + (size_t)N * 64;   // N*8
    float* a_dst1 = a_src1 + (size_t)N * 8;    // N*8
    float* h2w    = a_dst1 + (size_t)N * 8;    // N*16
    float* a_src2 = h2w    + (size_t)N * 16;   // N
    float* a_dst2 = a_src2 + (size_t)N;        // N
    int*   deg    = (int*)(a_dst2 + (size_t)N);// N
    int*   cursor = deg    + N;                // N
    int*   csum   = cursor + N;                // nb (<=128)
    int*   esrc   = csum   + 128;              // Etot

    // ---- CSR build ----
    hipMemsetAsync(deg, 0, (size_t)N * sizeof(int), stream);
    {
        int g = (Etot + 255) / 256;
        hist_kernel<<<g, 256, 0, stream>>>(ei, deg, E, Etot);
    }
    chunksum_kernel<<<nb, 256, 0, stream>>>(deg, csum, N);
    scan_csum_kernel<<<1, 128, 0, stream>>>(csum, nb);
    scan_chunk_kernel<<<nb, 256, 0, stream>>>(deg, csum, cursor, N);
    {
        int g = (Etot + 255) / 256;
        scatter_kernel<<<g, 256, 0, stream>>>(ei, cursor, esrc, E, Etot);
    }

    // ---- layer 1 ----
    gemm1_kernel<<<1024, 256, 0, stream>>>(x, W1, att_s1, att_d1, h1, a_src1, a_dst1, N);
    agg1_kernel<<<2048, 256, 0, stream>>>(esrc, cursor, deg, a_src1, a_dst1, h1, b1, h2, N);

    // ---- layer 2 ----
    gemm2_kernel<<<1024, 256, 0, stream>>>(h2, W2, att_s2, att_d2, h2w, a_src2, a_dst2, N);
    agg2_kernel<<<1024, 256, 0, stream>>>(esrc, cursor, deg, a_src2, a_dst2, h2w, b2, out, N);
}